// Round 5
// baseline (288.351 us; speedup 1.0000x reference)
//
#include <hip/hip_runtime.h>
#include <math.h>
#include <stdint.h>

#define B_ 16
#define L_ 50
#define LU_ 60
#define KU_ 100
#define DIM_ 60
#define V_ 2000
#define MAXVL_ 10
#define MIN_WL_ 4
#define MAX_WL_ 10
#define NE_ 7            // MAX_WL - MIN_WL + 1
#define IDC_ 3.5f
#define LOG_UNEXT_ (-4.6051701859880913680359829093687f)  // log(0.01)
#define CTXW_ 0.1f

// workspace layout (float element offsets)
#define WS_KU   0                 // ku_char_repr: 60*60 = 3600
#define WS_CLP  3600              // char_log_probs: 60*100 = 6000
#define WS_PLP  9600              // pos_lp: B*L*KU = 80000  (16B-aligned)
#define WS_BEST_BYTES (89600u * 4u)
#define BEST_STRIDE 8             // 64 B between per-batch atomic slots
#define WS_DONE_BYTES (WS_BEST_BYTES + 1024u)

#define URP_ 61   // padded LDS stride (odd -> conflict-free strided reads)
#define CWP_ 61
#define TSP_ 12   // transposed DP tile stride (48B: 16B-aligned columns)

// -------------------------------------------------------------------------
// Kernel 1 (60 blocks, one per LU row).
__global__ __launch_bounds__(128) void prep_kernel(
    const float* __restrict__ unit_repr,      // (KU, DIM)
    const float* __restrict__ aligner_weight, // (LU, KU)
    float* __restrict__ ws_f,
    unsigned long long* __restrict__ g_best,
    unsigned int* __restrict__ done_cnt,
    float* __restrict__ out_align)            // (LU, KU)
{
  __shared__ float s_ur[KU_ * URP_];
  __shared__ float s_aw[KU_];
  __shared__ float s_ku[DIM_];
  __shared__ float s_lg[KU_];
  __shared__ float sred[128];
  int r = blockIdx.x;
  int t = threadIdx.x;
  if (r == 0) {
    if (t < B_) g_best[t * BEST_STRIDE] = 0ull;
    if (t == 0) *done_cnt = 0u;
  }
  for (int i = t; i < KU_ * DIM_; i += 128)
    s_ur[(i / DIM_) * URP_ + (i % DIM_)] = unit_repr[i];
  if (t < KU_) s_aw[t] = aligner_weight[r * KU_ + t];
  __syncthreads();
  if (t < DIM_) {
    float acc = 0.f;
    for (int k = 0; k < KU_; ++k) acc += s_aw[k] * s_ur[k * URP_ + t];
    s_ku[t] = acc;
    ws_f[WS_KU + r * DIM_ + t] = acc;
  }
  __syncthreads();
  if (t < KU_) {
    float acc = 0.f;
    for (int d = 0; d < DIM_; ++d) acc += s_ku[d] * s_ur[t * URP_ + d];
    s_lg[t] = acc;
  }
  __syncthreads();
  sred[t] = (t < KU_) ? s_lg[t] : -1e30f;
  __syncthreads();
  for (int off = 64; off > 0; off >>= 1) {
    if (t < off) sred[t] = fmaxf(sred[t], sred[t + off]);
    __syncthreads();
  }
  float m = sred[0];
  __syncthreads();
  sred[t] = (t < KU_) ? expf(s_lg[t] - m) : 0.f;
  __syncthreads();
  for (int off = 64; off > 0; off >>= 1) {
    if (t < off) sred[t] += sred[t + off];
    __syncthreads();
  }
  float ls = m + logf(sred[0]);
  if (t < KU_) {
    float lp = s_lg[t] - ls;
    ws_f[WS_CLP + r * KU_ + t] = lp;
    out_align[r * KU_ + t] = expf(lp);
  }
}

// -------------------------------------------------------------------------
// Kernel 2: per (b,l), 256 threads. float4 staging of weights into LDS.
__global__ __launch_bounds__(256) void ctx_kernel(
    const int* __restrict__ uid,        // (B, L)
    const float* __restrict__ unit_repr,// (KU, DIM)
    const float* __restrict__ conv_w,   // (DIM, DIM, 3)
    const float* __restrict__ conv_b,   // (DIM,)
    const float* __restrict__ ws_f,
    float* __restrict__ ws_plp)         // (B*L, KU)
{
  int bl = blockIdx.x;
  int b = bl / L_, l = bl % L_;
  int t = threadIdx.x;
  __shared__ float s_ur[KU_ * URP_];
  __shared__ float s_cw[3 * DIM_ * CWP_];
  __shared__ float sx[3 * DIM_];
  __shared__ float swr[DIM_];
  __shared__ float slog[KU_];
  __shared__ float sred[256];

  const float4* ur4 = (const float4*)unit_repr;
  for (int k = t; k < (KU_ * DIM_) / 4; k += 256) {
    float4 v = ur4[k];
    int i0 = 4 * k;
    s_ur[((i0 + 0) / DIM_) * URP_ + ((i0 + 0) % DIM_)] = v.x;
    s_ur[((i0 + 1) / DIM_) * URP_ + ((i0 + 1) % DIM_)] = v.y;
    s_ur[((i0 + 2) / DIM_) * URP_ + ((i0 + 2) % DIM_)] = v.z;
    s_ur[((i0 + 3) / DIM_) * URP_ + ((i0 + 3) % DIM_)] = v.w;
  }
  const float4* cw4 = (const float4*)conv_w;
  for (int k = t; k < (DIM_ * DIM_ * 3) / 4; k += 256) {
    float4 v = cw4[k];
    int i0 = 4 * k;
    float vv[4] = {v.x, v.y, v.z, v.w};
#pragma unroll
    for (int e = 0; e < 4; ++e) {
      int idx = i0 + e;
      int o = idx / (3 * DIM_), id = idx % (3 * DIM_);
      s_cw[id * CWP_ + o] = vv[e];
    }
  }
  if (t < 3 * DIM_) {
    int d = t / DIM_, c = t % DIM_;
    int ld = l + d - 1;
    float vv = 0.f;
    if (ld >= 0 && ld < L_) {
      int u = uid[b * L_ + ld];
      vv = ws_f[WS_KU + u * DIM_ + c];
    }
    sx[t] = vv;
  }
  __syncthreads();
  if (t < DIM_) {
    float acc = conv_b[t];
    for (int i = 0; i < DIM_; ++i) {
      acc += sx[0 * DIM_ + i] * s_cw[(i * 3 + 0) * CWP_ + t];
      acc += sx[1 * DIM_ + i] * s_cw[(i * 3 + 1) * CWP_ + t];
      acc += sx[2 * DIM_ + i] * s_cw[(i * 3 + 2) * CWP_ + t];
    }
    swr[t] = acc;
  }
  __syncthreads();
  if (t < KU_) {
    float acc = 0.f;
    for (int d = 0; d < DIM_; ++d) acc += swr[d] * s_ur[t * URP_ + d];
    slog[t] = acc;
  }
  __syncthreads();
  sred[t] = (t < KU_) ? slog[t] : -1e30f;
  __syncthreads();
  for (int off = 128; off > 0; off >>= 1) {
    if (t < off) sred[t] = fmaxf(sred[t], sred[t + off]);
    __syncthreads();
  }
  float m = sred[0];
  __syncthreads();
  sred[t] = (t < KU_) ? expf(slog[t] - m) : 0.f;
  __syncthreads();
  for (int off = 128; off > 0; off >>= 1) {
    if (t < off) sred[t] += sred[t + off];
    __syncthreads();
  }
  float ls = m + logf(sred[0]);
  if (t < KU_) {
    int u = uid[b * L_ + l];
    float lp = slog[t] - ls;
    ws_plp[bl * KU_ + t] = ws_f[WS_CLP + u * KU_ + t] + CTXW_ * lp;
  }
}

// -------------------------------------------------------------------------
// Kernel 3: column-major DP on a transposed LDS tile, 2 vocab/thread,
// grid (B*L, 4). Last block (done-counter) also decodes the outputs.
__global__ __launch_bounds__(256, 4) void dp_kernel(
    const int* __restrict__ lengths,
    const int* __restrict__ vocab_ids,      // (V, MAXVL)
    const int* __restrict__ vocab_lengths,  // (V,)
    const float* __restrict__ ws_plp,       // (B*L, KU)
    unsigned long long* __restrict__ g_best,
    unsigned int* __restrict__ done_cnt,
    float* __restrict__ out)
{
  int bl = blockIdx.x;
  int b = bl / L_, l = bl % L_;
  int len_b = lengths[b];
  int imax = len_b - l;
  if (imax > MAX_WL_) imax = MAX_WL_;
  int t = threadIdx.x;
  __shared__ float sT[KU_ * TSP_];   // sT[k*12 + i]; rows >= imax are garbage
  __shared__ unsigned long long swave[4];
  __shared__ int s_last;

  if (imax >= MIN_WL_) {            // uniform across block
    int n = imax * KU_;
    for (int idx = t; idx < n; idx += 256) {
      int i = idx / KU_, k = idx - i * KU_;
      sT[k * TSP_ + i] = ws_plp[(bl + i) * KU_ + k];
    }
    __syncthreads();

    int v0 = blockIdx.y * 512 + t;       // < 2000 always
    int v1 = v0 + 256;
    bool has1 = (v1 < V_);
    // pack the 10 vocab char ids (<100) into 3 dwords each
    unsigned p0[3] = {0u, 0u, 0u}, p1[3] = {0u, 0u, 0u};
#pragma unroll
    for (int j = 0; j < MAXVL_; ++j)
      p0[j >> 2] |= ((unsigned)vocab_ids[v0 * MAXVL_ + j]) << ((j & 3) * 8);
    if (has1) {
#pragma unroll
      for (int j = 0; j < MAXVL_; ++j)
        p1[j >> 2] |= ((unsigned)vocab_ids[v1 * MAXVL_ + j]) << ((j & 3) * 8);
    }
    int vlen0 = vocab_lengths[v0];
    int vlen1 = has1 ? vocab_lengths[v1] : MIN_WL_;

    float A0[MAXVL_ + 1], A1[MAXVL_ + 1];
    float sv0[NE_], sv1[NE_];
#pragma unroll
    for (int e = 0; e < NE_; ++e) { sv0[e] = 0.f; sv1[e] = 0.f; }
#pragma unroll
    for (int i = 0; i <= MAXVL_; ++i) {
      A0[i] = -IDC_ * (float)i;
      A1[i] = A0[i];
    }

#pragma unroll
    for (int j = 1; j <= MAXVL_; ++j) {
      int k0 = (int)((p0[(j - 1) >> 2] >> (((j - 1) & 3) * 8)) & 0xFFu);
      int k1 = (int)((p1[(j - 1) >> 2] >> (((j - 1) & 3) * 8)) & 0xFFu);
      const float* c0 = &sT[k0 * TSP_];
      const float* c1 = &sT[k1 * TSP_];
      float4 a0 = *(const float4*)(c0);
      float4 m0 = *(const float4*)(c0 + 4);
      float2 e0 = *(const float2*)(c0 + 8);
      float4 a1 = *(const float4*)(c1);
      float4 m1 = *(const float4*)(c1 + 4);
      float2 e1 = *(const float2*)(c1 + 8);
      float s0[MAXVL_] = {a0.x, a0.y, a0.z, a0.w, m0.x, m0.y, m0.z, m0.w, e0.x, e0.y};
      float s1[MAXVL_] = {a1.x, a1.y, a1.z, a1.w, m1.x, m1.y, m1.z, m1.w, e1.x, e1.y};
      float B0[MAXVL_ + 1], B1[MAXVL_ + 1];
      B0[0] = -IDC_ * (float)j;
      B1[0] = B0[0];
#pragma unroll
      for (int i = 1; i <= MAXVL_; ++i) {
        B0[i] = fmaxf(A0[i - 1] + s0[i - 1], fmaxf(A0[i], B0[i - 1]) - IDC_);
        B1[i] = fmaxf(A1[i - 1] + s1[i - 1], fmaxf(A1[i], B1[i - 1]) - IDC_);
      }
      if (j == vlen0) {
#pragma unroll
        for (int e = 0; e < NE_; ++e) sv0[e] = B0[MIN_WL_ + e];
      }
      if (j == vlen1) {
#pragma unroll
        for (int e = 0; e < NE_; ++e) sv1[e] = B1[MIN_WL_ + e];
      }
#pragma unroll
      for (int i = 0; i <= MAXVL_; ++i) { A0[i] = B0[i]; A1[i] = B1[i]; }
    }

    unsigned long long bestKey = 0ull;
#pragma unroll
    for (int e = 0; e < NE_; ++e) {
      int i = MIN_WL_ + e;
      if (i <= imax) {
        float unext = (float)(len_b - i) * LOG_UNEXT_;
        unsigned int idx_base = (unsigned int)(l * (NE_ * V_) + e * V_);
        {
          float score = sv0[e] + unext;
          unsigned int u = __float_as_uint(score);
          u = (u & 0x80000000u) ? ~u : (u | 0x80000000u);
          unsigned long long key =
              ((unsigned long long)u << 32) |
              (unsigned long long)(~(idx_base + (unsigned int)v0));
          if (key > bestKey) bestKey = key;
        }
        if (has1) {
          float score = sv1[e] + unext;
          unsigned int u = __float_as_uint(score);
          u = (u & 0x80000000u) ? ~u : (u | 0x80000000u);
          unsigned long long key =
              ((unsigned long long)u << 32) |
              (unsigned long long)(~(idx_base + (unsigned int)v1));
          if (key > bestKey) bestKey = key;
        }
      }
    }

#pragma unroll
    for (int off = 32; off > 0; off >>= 1) {
      unsigned long long o = __shfl_down(bestKey, off);
      if (o > bestKey) bestKey = o;
    }
    int wid = t >> 6;
    if ((t & 63) == 0) swave[wid] = bestKey;
    __syncthreads();
    if (t == 0) {
      unsigned long long k0 = swave[0];
      for (int w = 1; w < 4; ++w)
        if (swave[w] > k0) k0 = swave[w];
      atomicMax(g_best + (size_t)b * BEST_STRIDE, k0);
    }
  }

  // ---- all blocks (including skipped ones): done-count; last block decodes
  __threadfence();
  if (t == 0) {
    unsigned int old = atomicAdd(done_cnt, 1u);
    s_last = (old == gridDim.x * gridDim.y - 1u) ? 1 : 0;
  }
  __syncthreads();
  if (s_last && t < B_) {
    __threadfence();
    // atomic fetch (max with 0 is a pure read) -> coherent across XCDs
    unsigned long long key = atomicMax(g_best + (size_t)t * BEST_STRIDE, 0ull);
    unsigned int u = (unsigned int)(key >> 32);
    unsigned int idx = ~((unsigned int)(key & 0xFFFFFFFFull));
    unsigned int bits = (u & 0x80000000u) ? (u & 0x7FFFFFFFu) : ~u;
    float val = __uint_as_float(bits);
    int start = (int)(idx / (NE_ * V_));
    int rem = (int)(idx % (NE_ * V_));
    int e = rem / V_;
    int vv = rem % V_;
    out[t] = (float)start;
    out[B_ + t] = (float)(start + MIN_WL_ + e - 1);
    out[2 * B_ + t] = val;
    out[3 * B_ + t] = (float)vv;
  }
}

// -------------------------------------------------------------------------
extern "C" void kernel_launch(void* const* d_in, const int* in_sizes, int n_in,
                              void* d_out, int out_size, void* d_ws, size_t ws_size,
                              hipStream_t stream)
{
  const int* uid            = (const int*)d_in[0];
  const int* lengths        = (const int*)d_in[1];
  const float* unit_repr    = (const float*)d_in[2];
  const float* aligner_w    = (const float*)d_in[3];
  const float* conv_w       = (const float*)d_in[4];
  const float* conv_b       = (const float*)d_in[5];
  const int* vocab_ids      = (const int*)d_in[6];
  const int* vocab_lengths  = (const int*)d_in[7];
  float* out = (float*)d_out;
  float* ws_f = (float*)d_ws;
  unsigned long long* g_best =
      (unsigned long long*)((char*)d_ws + WS_BEST_BYTES);
  unsigned int* done_cnt =
      (unsigned int*)((char*)d_ws + WS_DONE_BYTES);

  prep_kernel<<<LU_, 128, 0, stream>>>(unit_repr, aligner_w, ws_f, g_best,
                                       done_cnt, out + 4 * B_);
  ctx_kernel<<<B_ * L_, 256, 0, stream>>>(uid, unit_repr, conv_w, conv_b, ws_f,
                                          ws_f + WS_PLP);
  dim3 g3(B_ * L_, 4);
  dp_kernel<<<g3, 256, 0, stream>>>(lengths, vocab_ids, vocab_lengths,
                                    ws_f + WS_PLP, g_best, done_cnt, out);
}

// Round 6
// 111.900 us; speedup vs baseline: 2.5769x; 2.5769x over previous
//
#include <hip/hip_runtime.h>
#include <math.h>
#include <stdint.h>

#define B_ 16
#define L_ 50
#define LU_ 60
#define KU_ 100
#define DIM_ 60
#define V_ 2000
#define MAXVL_ 10
#define MIN_WL_ 4
#define MAX_WL_ 10
#define NE_ 7            // MAX_WL - MIN_WL + 1
#define IDC_ 3.5f
#define LOG_UNEXT_ (-4.6051701859880913680359829093687f)  // log(0.01)
#define CTXW_ 0.1f

// workspace layout (float element offsets)
#define WS_KU   0                 // ku_char_repr: 60*60 = 3600
#define WS_CLP  3600              // char_log_probs: 60*100 = 6000
#define WS_PLP  9600              // pos_lp: B*L*KU = 80000  (16B-aligned)
#define WS_BEST_BYTES (89600u * 4u)
#define BEST_STRIDE 8             // 64 B between per-batch atomic slots

#define URP_ 61   // padded LDS stride (odd -> conflict-free strided reads)
#define CWP_ 61
#define TSP_ 12   // transposed DP tile stride (48B: 16B-aligned columns)

// -------------------------------------------------------------------------
// Kernel 1 (60 blocks, one per LU row).
__global__ __launch_bounds__(128) void prep_kernel(
    const float* __restrict__ unit_repr,      // (KU, DIM)
    const float* __restrict__ aligner_weight, // (LU, KU)
    float* __restrict__ ws_f,
    unsigned long long* __restrict__ g_best,
    float* __restrict__ out_align)            // (LU, KU)
{
  __shared__ float s_ur[KU_ * URP_];
  __shared__ float s_aw[KU_];
  __shared__ float s_ku[DIM_];
  __shared__ float s_lg[KU_];
  __shared__ float sred[128];
  int r = blockIdx.x;
  int t = threadIdx.x;
  if (r == 0 && t < B_) g_best[t * BEST_STRIDE] = 0ull;
  for (int i = t; i < KU_ * DIM_; i += 128)
    s_ur[(i / DIM_) * URP_ + (i % DIM_)] = unit_repr[i];
  if (t < KU_) s_aw[t] = aligner_weight[r * KU_ + t];
  __syncthreads();
  if (t < DIM_) {
    float acc = 0.f;
    for (int k = 0; k < KU_; ++k) acc += s_aw[k] * s_ur[k * URP_ + t];
    s_ku[t] = acc;
    ws_f[WS_KU + r * DIM_ + t] = acc;
  }
  __syncthreads();
  if (t < KU_) {
    float acc = 0.f;
    for (int d = 0; d < DIM_; ++d) acc += s_ku[d] * s_ur[t * URP_ + d];
    s_lg[t] = acc;
  }
  __syncthreads();
  sred[t] = (t < KU_) ? s_lg[t] : -1e30f;
  __syncthreads();
  for (int off = 64; off > 0; off >>= 1) {
    if (t < off) sred[t] = fmaxf(sred[t], sred[t + off]);
    __syncthreads();
  }
  float m = sred[0];
  __syncthreads();
  sred[t] = (t < KU_) ? expf(s_lg[t] - m) : 0.f;
  __syncthreads();
  for (int off = 64; off > 0; off >>= 1) {
    if (t < off) sred[t] += sred[t + off];
    __syncthreads();
  }
  float ls = m + logf(sred[0]);
  if (t < KU_) {
    float lp = s_lg[t] - ls;
    ws_f[WS_CLP + r * KU_ + t] = lp;
    out_align[r * KU_ + t] = expf(lp);
  }
}

// -------------------------------------------------------------------------
// Kernel 2: per (b,l), 256 threads. float4 staging of weights into LDS.
__global__ __launch_bounds__(256) void ctx_kernel(
    const int* __restrict__ uid,        // (B, L)
    const float* __restrict__ unit_repr,// (KU, DIM)
    const float* __restrict__ conv_w,   // (DIM, DIM, 3)
    const float* __restrict__ conv_b,   // (DIM,)
    const float* __restrict__ ws_f,
    float* __restrict__ ws_plp)         // (B*L, KU)
{
  int bl = blockIdx.x;
  int b = bl / L_, l = bl % L_;
  int t = threadIdx.x;
  __shared__ float s_ur[KU_ * URP_];
  __shared__ float s_cw[3 * DIM_ * CWP_];
  __shared__ float sx[3 * DIM_];
  __shared__ float swr[DIM_];
  __shared__ float slog[KU_];
  __shared__ float sred[256];

  const float4* ur4 = (const float4*)unit_repr;
  for (int k = t; k < (KU_ * DIM_) / 4; k += 256) {
    float4 v = ur4[k];
    int i0 = 4 * k;
    s_ur[((i0 + 0) / DIM_) * URP_ + ((i0 + 0) % DIM_)] = v.x;
    s_ur[((i0 + 1) / DIM_) * URP_ + ((i0 + 1) % DIM_)] = v.y;
    s_ur[((i0 + 2) / DIM_) * URP_ + ((i0 + 2) % DIM_)] = v.z;
    s_ur[((i0 + 3) / DIM_) * URP_ + ((i0 + 3) % DIM_)] = v.w;
  }
  const float4* cw4 = (const float4*)conv_w;
  for (int k = t; k < (DIM_ * DIM_ * 3) / 4; k += 256) {
    float4 v = cw4[k];
    int i0 = 4 * k;
    float vv[4] = {v.x, v.y, v.z, v.w};
#pragma unroll
    for (int e = 0; e < 4; ++e) {
      int idx = i0 + e;
      int o = idx / (3 * DIM_), id = idx % (3 * DIM_);
      s_cw[id * CWP_ + o] = vv[e];
    }
  }
  if (t < 3 * DIM_) {
    int d = t / DIM_, c = t % DIM_;
    int ld = l + d - 1;
    float vv = 0.f;
    if (ld >= 0 && ld < L_) {
      int u = uid[b * L_ + ld];
      vv = ws_f[WS_KU + u * DIM_ + c];
    }
    sx[t] = vv;
  }
  __syncthreads();
  if (t < DIM_) {
    float acc = conv_b[t];
    for (int i = 0; i < DIM_; ++i) {
      acc += sx[0 * DIM_ + i] * s_cw[(i * 3 + 0) * CWP_ + t];
      acc += sx[1 * DIM_ + i] * s_cw[(i * 3 + 1) * CWP_ + t];
      acc += sx[2 * DIM_ + i] * s_cw[(i * 3 + 2) * CWP_ + t];
    }
    swr[t] = acc;
  }
  __syncthreads();
  if (t < KU_) {
    float acc = 0.f;
    for (int d = 0; d < DIM_; ++d) acc += swr[d] * s_ur[t * URP_ + d];
    slog[t] = acc;
  }
  __syncthreads();
  sred[t] = (t < KU_) ? slog[t] : -1e30f;
  __syncthreads();
  for (int off = 128; off > 0; off >>= 1) {
    if (t < off) sred[t] = fmaxf(sred[t], sred[t + off]);
    __syncthreads();
  }
  float m = sred[0];
  __syncthreads();
  sred[t] = (t < KU_) ? expf(slog[t] - m) : 0.f;
  __syncthreads();
  for (int off = 128; off > 0; off >>= 1) {
    if (t < off) sred[t] += sred[t + off];
    __syncthreads();
  }
  float ls = m + logf(sred[0]);
  if (t < KU_) {
    int u = uid[b * L_ + l];
    float lp = slog[t] - ls;
    ws_plp[bl * KU_ + t] = ws_f[WS_CLP + u * KU_ + t] + CTXW_ * lp;
  }
}

// -------------------------------------------------------------------------
// Kernel 3: column-major DP on a transposed LDS tile, 2 vocab/thread,
// grid (B*L, 4). NO device-scope fences here (round-5 lesson: a per-wave
// __threadfence storm costs ~190 us in L2 writebacks on 8-XCD gfx950).
__global__ __launch_bounds__(256) void dp_kernel(
    const int* __restrict__ lengths,
    const int* __restrict__ vocab_ids,      // (V, MAXVL)
    const int* __restrict__ vocab_lengths,  // (V,)
    const float* __restrict__ ws_plp,       // (B*L, KU)
    unsigned long long* __restrict__ g_best)
{
  int bl = blockIdx.x;
  int b = bl / L_, l = bl % L_;
  int len_b = lengths[b];
  int imax = len_b - l;
  if (imax > MAX_WL_) imax = MAX_WL_;
  if (imax < MIN_WL_) return;       // uniform across block

  __shared__ float sT[KU_ * TSP_];  // sT[k*12 + i]; rows >= imax are garbage
  __shared__ unsigned long long swave[4];
  int t = threadIdx.x;
  {
    int n = imax * KU_;
    for (int idx = t; idx < n; idx += 256) {
      int i = idx / KU_, k = idx - i * KU_;
      sT[k * TSP_ + i] = ws_plp[(bl + i) * KU_ + k];
    }
  }
  __syncthreads();

  int v0 = blockIdx.y * 512 + t;    // < 2000 always
  int v1 = v0 + 256;
  bool has1 = (v1 < V_);
  int vid0[MAXVL_], vid1[MAXVL_];
#pragma unroll
  for (int j = 0; j < MAXVL_; ++j) vid0[j] = vocab_ids[v0 * MAXVL_ + j];
  if (has1) {
#pragma unroll
    for (int j = 0; j < MAXVL_; ++j) vid1[j] = vocab_ids[v1 * MAXVL_ + j];
  } else {
#pragma unroll
    for (int j = 0; j < MAXVL_; ++j) vid1[j] = 0;
  }
  int vlen0 = vocab_lengths[v0];
  int vlen1 = has1 ? vocab_lengths[v1] : MIN_WL_;

  float A0[MAXVL_ + 1], A1[MAXVL_ + 1];
  float sv0[NE_], sv1[NE_];
#pragma unroll
  for (int e = 0; e < NE_; ++e) { sv0[e] = 0.f; sv1[e] = 0.f; }
#pragma unroll
  for (int i = 0; i <= MAXVL_; ++i) {
    A0[i] = -IDC_ * (float)i;
    A1[i] = A0[i];
  }

#pragma unroll
  for (int j = 1; j <= MAXVL_; ++j) {
    const float* c0 = &sT[vid0[j - 1] * TSP_];
    const float* c1 = &sT[vid1[j - 1] * TSP_];
    float4 a0 = *(const float4*)(c0);
    float4 m0 = *(const float4*)(c0 + 4);
    float2 e0 = *(const float2*)(c0 + 8);
    float4 a1 = *(const float4*)(c1);
    float4 m1 = *(const float4*)(c1 + 4);
    float2 e1 = *(const float2*)(c1 + 8);
    float s0[MAXVL_] = {a0.x, a0.y, a0.z, a0.w, m0.x, m0.y, m0.z, m0.w, e0.x, e0.y};
    float s1[MAXVL_] = {a1.x, a1.y, a1.z, a1.w, m1.x, m1.y, m1.z, m1.w, e1.x, e1.y};
    float B0[MAXVL_ + 1], B1[MAXVL_ + 1];
    B0[0] = -IDC_ * (float)j;
    B1[0] = B0[0];
#pragma unroll
    for (int i = 1; i <= MAXVL_; ++i) {
      B0[i] = fmaxf(A0[i - 1] + s0[i - 1], fmaxf(A0[i], B0[i - 1]) - IDC_);
      B1[i] = fmaxf(A1[i - 1] + s1[i - 1], fmaxf(A1[i], B1[i - 1]) - IDC_);
    }
    if (j == vlen0) {
#pragma unroll
      for (int e = 0; e < NE_; ++e) sv0[e] = B0[MIN_WL_ + e];
    }
    if (j == vlen1) {
#pragma unroll
      for (int e = 0; e < NE_; ++e) sv1[e] = B1[MIN_WL_ + e];
    }
#pragma unroll
    for (int i = 0; i <= MAXVL_; ++i) { A0[i] = B0[i]; A1[i] = B1[i]; }
  }

  unsigned long long bestKey = 0ull;
#pragma unroll
  for (int e = 0; e < NE_; ++e) {
    int i = MIN_WL_ + e;
    if (i <= imax) {
      float unext = (float)(len_b - i) * LOG_UNEXT_;
      unsigned int idx_base = (unsigned int)(l * (NE_ * V_) + e * V_);
      {
        float score = sv0[e] + unext;
        unsigned int u = __float_as_uint(score);
        u = (u & 0x80000000u) ? ~u : (u | 0x80000000u);
        unsigned long long key =
            ((unsigned long long)u << 32) |
            (unsigned long long)(~(idx_base + (unsigned int)v0));
        if (key > bestKey) bestKey = key;
      }
      if (has1) {
        float score = sv1[e] + unext;
        unsigned int u = __float_as_uint(score);
        u = (u & 0x80000000u) ? ~u : (u | 0x80000000u);
        unsigned long long key =
            ((unsigned long long)u << 32) |
            (unsigned long long)(~(idx_base + (unsigned int)v1));
        if (key > bestKey) bestKey = key;
      }
    }
  }

#pragma unroll
  for (int off = 32; off > 0; off >>= 1) {
    unsigned long long o = __shfl_down(bestKey, off);
    if (o > bestKey) bestKey = o;
  }
  int wid = t >> 6;
  if ((t & 63) == 0) swave[wid] = bestKey;
  __syncthreads();
  if (t == 0) {
    unsigned long long k0 = swave[0];
    for (int w = 1; w < 4; ++w)
      if (swave[w] > k0) k0 = swave[w];
    atomicMax(g_best + (size_t)b * BEST_STRIDE, k0);
  }
}

// -------------------------------------------------------------------------
// Kernel 4: decode. Separate launch = implicit device-wide fence (cheap).
__global__ void decode_kernel(const unsigned long long* __restrict__ g_best,
                              float* __restrict__ out)
{
  int t = threadIdx.x;
  if (t < B_) {
    unsigned long long key = g_best[t * BEST_STRIDE];
    unsigned int u = (unsigned int)(key >> 32);
    unsigned int idx = ~((unsigned int)(key & 0xFFFFFFFFull));
    unsigned int bits = (u & 0x80000000u) ? (u & 0x7FFFFFFFu) : ~u;
    float val = __uint_as_float(bits);
    int start = (int)(idx / (NE_ * V_));
    int rem = (int)(idx % (NE_ * V_));
    int e = rem / V_;
    int vv = rem % V_;
    out[t] = (float)start;
    out[B_ + t] = (float)(start + MIN_WL_ + e - 1);
    out[2 * B_ + t] = val;
    out[3 * B_ + t] = (float)vv;
  }
}

// -------------------------------------------------------------------------
extern "C" void kernel_launch(void* const* d_in, const int* in_sizes, int n_in,
                              void* d_out, int out_size, void* d_ws, size_t ws_size,
                              hipStream_t stream)
{
  const int* uid            = (const int*)d_in[0];
  const int* lengths        = (const int*)d_in[1];
  const float* unit_repr    = (const float*)d_in[2];
  const float* aligner_w    = (const float*)d_in[3];
  const float* conv_w       = (const float*)d_in[4];
  const float* conv_b       = (const float*)d_in[5];
  const int* vocab_ids      = (const int*)d_in[6];
  const int* vocab_lengths  = (const int*)d_in[7];
  float* out = (float*)d_out;
  float* ws_f = (float*)d_ws;
  unsigned long long* g_best =
      (unsigned long long*)((char*)d_ws + WS_BEST_BYTES);

  prep_kernel<<<LU_, 128, 0, stream>>>(unit_repr, aligner_w, ws_f, g_best,
                                       out + 4 * B_);
  ctx_kernel<<<B_ * L_, 256, 0, stream>>>(uid, unit_repr, conv_w, conv_b, ws_f,
                                          ws_f + WS_PLP);
  dim3 g3(B_ * L_, 4);
  dp_kernel<<<g3, 256, 0, stream>>>(lengths, vocab_ids, vocab_lengths,
                                    ws_f + WS_PLP, g_best);
  decode_kernel<<<1, 64, 0, stream>>>(g_best, out);
}